// Round 3
// baseline (1186.926 us; speedup 1.0000x reference)
//
#include <hip/hip_runtime.h>
#include <stdint.h>

typedef __attribute__((ext_vector_type(8))) short short8;
typedef __attribute__((ext_vector_type(4))) float floatx4;

__device__ __forceinline__ unsigned short f2bf(float x) {
  unsigned int u = __float_as_uint(x);
  u += 0x7fffu + ((u >> 16) & 1u);   // RNE
  return (unsigned short)(u >> 16);
}
__device__ __forceinline__ float bf2f(unsigned short b) {
  return __uint_as_float(((unsigned int)b) << 16);
}

// h fp32 [N,256] -> bf16 [N,256] row-major (8 elems/thread)
__global__ void hcvt_kernel(const float* __restrict__ h,
                            unsigned short* __restrict__ o, int total8) {
  int u = blockIdx.x * 256 + threadIdx.x;
  if (u >= total8) return;
  const float4* h4 = (const float4*)h;
  float4 v0 = h4[u * 2], v1 = h4[u * 2 + 1];
  short8 s;
  s[0] = (short)f2bf(v0.x); s[1] = (short)f2bf(v0.y);
  s[2] = (short)f2bf(v0.z); s[3] = (short)f2bf(v0.w);
  s[4] = (short)f2bf(v1.x); s[5] = (short)f2bf(v1.y);
  s[6] = (short)f2bf(v1.z); s[7] = (short)f2bf(v1.w);
  ((short8*)o)[u] = s;
}

// W [K][256] fp32 -> fragment-major bf16:
// flat u = ((k32*256 + n)*4 + kq)*8 + j  holds  W[k32*32 + kq*8 + j][n].
// A wave's B-fragment load (lane: n=ntile+lm, kq=lq) is a coalesced 1 KB.
__global__ void wfrag_kernel(const float* __restrict__ W,
                             unsigned short* __restrict__ out, int total) {
  int u = blockIdx.x * 256 + threadIdx.x;
  if (u >= total) return;
  int j   = u & 7;
  int kq  = (u >> 3) & 3;
  int n   = (u >> 5) & 255;
  int k32 = u >> 13;
  int k   = k32 * 32 + kq * 8 + j;
  out[u] = f2bf(W[k * 256 + n]);
}

// Persistent pipelined kernel. LDS: A 64x512 bf16 (64 KB, X overlays first 32 KB),
// w3 (2 KB), iobuf 2x128 ints (1 KB) -> 68.6 KB -> 2 blocks/CU.
// Pipeline: gather for tile i+1 issues into VGPRs right after tile i's A-stage,
// drains during tile i's L1 MFMA phase; ioff double-buffered two tiles ahead.
template <bool HBF>
__global__ __launch_bounds__(256, 2)
void edge_mlp_kernel(const void* __restrict__ hsrc,
                     const int* __restrict__ dst,
                     const int* __restrict__ src,
                     const unsigned short* __restrict__ W1F,
                     const unsigned short* __restrict__ W2F,
                     const float* __restrict__ W3,
                     float* __restrict__ out, int ntiles) {
  __shared__ unsigned short A[64 * 512];
  __shared__ float w3s[512];
  __shared__ int iobuf[2][128];
  unsigned short* X = A;  // overlay, row stride 256

  const int t    = threadIdx.x;
  const int lane = t & 63;
  const int w    = t >> 6;
  const int lq   = lane >> 4;
  const int lm   = lane & 15;
  const int bid  = blockIdx.x;
  const int stride = gridDim.x;
  const int nIter  = (ntiles - bid + stride - 1) / stride;

  w3s[t] = W3[t];
  w3s[t + 256] = W3[t + 256];
  if (t < 128) {
    const int* p = (t < 64) ? dst : src;
    iobuf[0][t] = p[bid * 64 + (t & 63)];
    if (nIter > 1) iobuf[1][t] = p[(bid + stride) * 64 + (t & 63)];
  }

  const short8* B1 = (const short8*)W1F;
  const short8* B2 = (const short8*)W2F;

  short8 g[16];
  auto issue_gather = [&](int nb) {
    const int half = (lane >= 32) ? 64 : 0;
    const int cc   = lane & 31;
#pragma unroll
    for (int it = 0; it < 16; ++it) {
      int r = it * 4 + w;                 // wave-uniform -> 2x512B coalesced
      int node = iobuf[nb][half + r];
      if (HBF) {
        g[it] = ((const short8*)hsrc)[node * 32 + cc];
      } else {
        const float4* h4 = (const float4*)hsrc;
        float4 v0 = h4[node * 64 + cc * 2];
        float4 v1 = h4[node * 64 + cc * 2 + 1];
        short8 s;
        s[0] = (short)f2bf(v0.x); s[1] = (short)f2bf(v0.y);
        s[2] = (short)f2bf(v0.z); s[3] = (short)f2bf(v0.w);
        s[4] = (short)f2bf(v1.x); s[5] = (short)f2bf(v1.y);
        s[6] = (short)f2bf(v1.z); s[7] = (short)f2bf(v1.w);
        g[it] = s;
      }
    }
  };

  __syncthreads();
  issue_gather(0);  // tile 0

  for (int i = 0; i < nIter; ++i) {
    const int tile = bid + i * stride;
    const int m0   = tile * 64;
    __syncthreads();  // prior tile's X reads + out stores done
    // ---- Stage A from prefetched registers
    {
      const int c = lane;
#pragma unroll
      for (int it = 0; it < 16; ++it) {
        int r = it * 4 + w;
        *(short8*)&A[r * 512 + ((c ^ (r & 7)) << 3)] = g[it];
      }
    }
    // ---- ioff for tile i+2 -> regs (overlaps barrier)
    int ioreg = 0;
    const bool have2 = (i + 2) < nIter;
    if (have2 && t < 128) {
      const int* p = (t < 64) ? dst : src;
      ioreg = p[(bid + (i + 2) * stride) * 64 + (t & 63)];
    }
    __syncthreads();  // A visible
    // ---- Prefetch gather for tile i+1 (drains during L1 compute)
    if ((i + 1) < nIter) issue_gather((i + 1) & 1);
    if (have2 && t < 128) iobuf[i & 1][t] = ioreg;

    floatx4 acc[4][4];
#pragma unroll
    for (int ii = 0; ii < 4; ++ii)
#pragma unroll
      for (int jj = 0; jj < 4; ++jj) acc[ii][jj] = (floatx4)(0.0f);

    // ---- Layer 1: K=512, 16 k-steps, B from global (L2), no inner barriers
    auto loadB1 = [&](short8* b, int k32) {
#pragma unroll
      for (int jt = 0; jt < 4; ++jt)
        b[jt] = B1[(k32 * 256 + w * 64 + jt * 16 + lm) * 4 + lq];
    };
    auto stepL1 = [&](int k32, const short8* b) {
      short8 af[4];
#pragma unroll
      for (int ii = 0; ii < 4; ++ii) {
        int r = ii * 16 + lm;
        int c = k32 * 4 + lq;
        af[ii] = *(const short8*)&A[r * 512 + ((c ^ (r & 7)) << 3)];
      }
#pragma unroll
      for (int ii = 0; ii < 4; ++ii)
#pragma unroll
        for (int jj = 0; jj < 4; ++jj)
          acc[ii][jj] = __builtin_amdgcn_mfma_f32_16x16x32_bf16(af[ii], b[jj], acc[ii][jj], 0, 0, 0);
    };
    {
      short8 b0[4], b1[4];
      loadB1(b0, 0);
#pragma unroll
      for (int k2 = 0; k2 < 8; ++k2) {
        loadB1(b1, k2 * 2 + 1);
        stepL1(k2 * 2, b0);
        loadB1(b0, (k2 * 2 + 2) & 15);
        stepL1(k2 * 2 + 1, b1);
      }
    }

    __syncthreads();  // all A reads done; X overlays A
#pragma unroll
    for (int ii = 0; ii < 4; ++ii) {
      int row0 = ii * 16 + lq * 4;
#pragma unroll
      for (int jj = 0; jj < 4; ++jj) {
        int col = w * 64 + jj * 16 + lm;
        int cch = col >> 3, ce = col & 7;
#pragma unroll
        for (int rg = 0; rg < 4; ++rg) {
          int row = row0 + rg;
          float v = acc[ii][jj][rg];
          v = v > 0.0f ? v : 0.0f;
          X[row * 256 + (((cch ^ (row & 7)) << 3) | ce)] = f2bf(v);
        }
      }
    }
#pragma unroll
    for (int ii = 0; ii < 4; ++ii)
#pragma unroll
      for (int jj = 0; jj < 4; ++jj) acc[ii][jj] = (floatx4)(0.0f);
    __syncthreads();

    // ---- Layer 2: K=256, 8 k-steps, A from X (LDS), B from global
    auto loadB2 = [&](short8* b, int k32) {
#pragma unroll
      for (int jt = 0; jt < 4; ++jt)
        b[jt] = B2[(k32 * 256 + w * 64 + jt * 16 + lm) * 4 + lq];
    };
    auto stepL2 = [&](int k32, const short8* b) {
      short8 af[4];
#pragma unroll
      for (int ii = 0; ii < 4; ++ii) {
        int r = ii * 16 + lm;
        int c = k32 * 4 + lq;
        af[ii] = *(const short8*)&X[r * 256 + ((c ^ (r & 7)) << 3)];
      }
#pragma unroll
      for (int ii = 0; ii < 4; ++ii)
#pragma unroll
        for (int jj = 0; jj < 4; ++jj)
          acc[ii][jj] = __builtin_amdgcn_mfma_f32_16x16x32_bf16(af[ii], b[jj], acc[ii][jj], 0, 0, 0);
    };
    {
      short8 b0[4], b1[4];
      loadB2(b0, 0);
#pragma unroll
      for (int k2 = 0; k2 < 4; ++k2) {
        loadB2(b1, k2 * 2 + 1);
        stepL2(k2 * 2, b0);
        loadB2(b0, (k2 * 2 + 2) & 7);
        stepL2(k2 * 2 + 1, b1);
      }
    }

    __syncthreads();
#pragma unroll
    for (int ii = 0; ii < 4; ++ii) {
      int row0 = ii * 16 + lq * 4;
#pragma unroll
      for (int jj = 0; jj < 4; ++jj) {
        int col = w * 64 + jj * 16 + lm;
        int cch = col >> 3, ce = col & 7;
#pragma unroll
        for (int rg = 0; rg < 4; ++rg) {
          int row = row0 + rg;
          float v = acc[ii][jj][rg];
          v = v > 0.0f ? v : 0.0f;
          X[row * 256 + (((cch ^ (row & 7)) << 3) | ce)] = f2bf(v);
        }
      }
    }
    __syncthreads();

    // ---- Layer 3: out = X @ W3 (fp32 VALU, N=2)
    {
      int r = t >> 2, o = (t >> 1) & 1, hh = t & 1;
      float s = 0.0f;
#pragma unroll
      for (int it = 0; it < 16; ++it) {
        int c = hh * 16 + it;
        short8 xv = *(const short8*)&X[r * 256 + ((c ^ (r & 7)) << 3)];
#pragma unroll
        for (int e = 0; e < 8; ++e)
          s += bf2f((unsigned short)xv[e]) * w3s[((c << 3) + e) * 2 + o];
      }
      s += __shfl_xor(s, 1);
      if (hh == 0) out[(m0 + r) * 2 + o] = s;
    }
  }
}

extern "C" void kernel_launch(void* const* d_in, const int* in_sizes, int n_in,
                              void* d_out, int out_size, void* d_ws, size_t ws_size,
                              hipStream_t stream) {
  const float* h   = (const float*)d_in[0];
  const int*   dst = (const int*)d_in[1];
  const int*   src = (const int*)d_in[2];
  const float* W1  = (const float*)d_in[3];
  const float* W2  = (const float*)d_in[4];
  const float* W3  = (const float*)d_in[5];
  float* out = (float*)d_out;

  const int h_elems = in_sizes[0];
  const int n_pairs = in_sizes[1];
  const int ntiles  = n_pairs / 64;
  const int grid    = ntiles < 512 ? ntiles : 512;   // 2 persistent blocks/CU

  const size_t hbf_elems = (size_t)h_elems;
  const bool use_hbf = ws_size >= (hbf_elems + 131072 + 65536) * sizeof(unsigned short);

  unsigned short* HBF = (unsigned short*)d_ws;
  unsigned short* W1F = use_hbf ? HBF + hbf_elems : (unsigned short*)d_ws;
  unsigned short* W2F = W1F + 131072;

  wfrag_kernel<<<512, 256, 0, stream>>>(W1, W1F, 131072);
  wfrag_kernel<<<256, 256, 0, stream>>>(W2, W2F, 65536);

  if (use_hbf) {
    int total8 = h_elems / 8;
    hcvt_kernel<<<(total8 + 255) / 256, 256, 0, stream>>>(h, HBF, total8);
    edge_mlp_kernel<true><<<grid, 256, 0, stream>>>(HBF, dst, src, W1F, W2F, W3, out, ntiles);
  } else {
    edge_mlp_kernel<false><<<grid, 256, 0, stream>>>(h, dst, src, W1F, W2F, W3, out, ntiles);
  }
}

// Round 4
// 930.204 us; speedup vs baseline: 1.2760x; 1.2760x over previous
//
#include <hip/hip_runtime.h>
#include <stdint.h>

typedef __attribute__((ext_vector_type(8))) short short8;
typedef __attribute__((ext_vector_type(4))) float floatx4;

__device__ __forceinline__ unsigned short f2bf(float x) {
  unsigned int u = __float_as_uint(x);
  u += 0x7fffu + ((u >> 16) & 1u);   // RNE
  return (unsigned short)(u >> 16);
}
__device__ __forceinline__ float bf2f(unsigned short b) {
  return __uint_as_float(((unsigned int)b) << 16);
}
__device__ __forceinline__ void gload_lds16(const void* g, void* lds) {
  __builtin_amdgcn_global_load_lds(
      (const __attribute__((address_space(1))) unsigned int*)g,
      (__attribute__((address_space(3))) unsigned int*)lds, 16, 0, 0);
}

// h fp32 [N,256] -> bf16 [N,256] row-major
__global__ void hcvt_kernel(const float* __restrict__ h,
                            unsigned short* __restrict__ o, int total8) {
  int u = blockIdx.x * 256 + threadIdx.x;
  if (u >= total8) return;
  const float4* h4 = (const float4*)h;
  float4 v0 = h4[u * 2], v1 = h4[u * 2 + 1];
  short8 s;
  s[0] = (short)f2bf(v0.x); s[1] = (short)f2bf(v0.y);
  s[2] = (short)f2bf(v0.z); s[3] = (short)f2bf(v0.w);
  s[4] = (short)f2bf(v1.x); s[5] = (short)f2bf(v1.y);
  s[6] = (short)f2bf(v1.z); s[7] = (short)f2bf(v1.w);
  ((short8*)o)[u] = s;
}

// W [K][256] fp32 -> fragment-major bf16: u = ((k32*256+n)*4+kq)*8+j holds W[k32*32+kq*8+j][n]
__global__ void wfrag_kernel(const float* __restrict__ W,
                             unsigned short* __restrict__ out, int total) {
  int u = blockIdx.x * 256 + threadIdx.x;
  if (u >= total) return;
  int j   = u & 7;
  int kq  = (u >> 3) & 3;
  int n   = (u >> 5) & 255;
  int k32 = u >> 13;
  int k   = k32 * 32 + kq * 8 + j;
  out[u] = f2bf(W[k * 256 + n]);
}

// ---------------- Main pipelined kernel ----------------
// 512 threads (8 waves), 1 block/CU. LDS: A[2][64KB] frag-major + w3s = 130 KB.
// A frag (k32 0..15, ii 0..3): lane L holds h[node(ii*16+(L&15))][(k32&7)*32+(L>>4)*8 ..+8]
//   at Abuf + frag*1024 + L*16  (global_load_lds, zero VGPR cost, conflict-free reads).
// X (64x256 bf16, R2 swizzle) overlays A[cur] upper 32 KB after L1.
// Gathers for tile i+1 interleave into tile i's L1; B quad-buffered so in-order
// vmcnt waits keep gathers in flight ~4 k-steps.
__global__ __launch_bounds__(512, 2)
void edge_mlp_pipe(const unsigned short* __restrict__ hbf,
                   const int* __restrict__ dst,
                   const int* __restrict__ src,
                   const unsigned short* __restrict__ W1F,
                   const unsigned short* __restrict__ W2F,
                   const float* __restrict__ W3,
                   float* __restrict__ out, int ntiles) {
  __shared__ unsigned short Abuf[2][64 * 512];
  __shared__ float w3s[512];

  const int t    = threadIdx.x;
  const int lane = t & 63;
  const int w    = t >> 6;          // 8 waves; wave w -> cols w*32..+32
  const int lq   = lane >> 4;
  const int lm   = lane & 15;
  const int bid  = blockIdx.x;
  const int stride = gridDim.x;
  const int nIter  = (ntiles - bid + stride - 1) / stride;
  const int last   = nIter - 1;

  w3s[t] = W3[t];

  // waves 0..3 gather dst-half frags (k32<8), waves 4..7 src-half
  const int* idxsrc = (w < 4) ? dst : src;
  int n1[4], n2[4];
  auto loadIdx = [&](int* n, int it) {
    int mm = (bid + it * stride) * 64;
#pragma unroll
    for (int ii = 0; ii < 4; ++ii) n[ii] = idxsrc[mm + ii * 16 + lm];
  };
  auto gatherTo = [&](char* Anx, const int* n, int u) {
    int frag = w * 8 + u, k32 = frag >> 2, ii = frag & 3;
    const char* g = (const char*)hbf + (size_t)n[ii] * 512 + (k32 & 7) * 64 + lq * 16;
    gload_lds16(g, Anx + frag * 1024);
  };

  {
    int n0[4];
    loadIdx(n0, 0);
    loadIdx(n1, last >= 1 ? 1 : 0);
    loadIdx(n2, last >= 2 ? 2 : last);
#pragma unroll
    for (int u = 0; u < 8; ++u) gatherTo((char*)&Abuf[0][0], n0, u);
  }
  __syncthreads();   // drains tile-0 gathers; w3s visible

  const short8* B1 = (const short8*)W1F;
  const short8* B2 = (const short8*)W2F;

  for (int i = 0; i < nIter; ++i) {
    const int cur = i & 1;
    const unsigned short* Ac = &Abuf[cur][0];
    char* An = (char*)&Abuf[cur ^ 1][0];
    unsigned short* X = &Abuf[cur][16384];   // upper 32 KB overlay
    const int m0 = (bid + i * stride) * 64;
    const bool pre = (i + 1) < nIter;

    floatx4 acc[4][2];
#pragma unroll
    for (int ii = 0; ii < 4; ++ii)
#pragma unroll
      for (int j = 0; j < 2; ++j) acc[ii][j] = (floatx4)(0.0f);

    // ---- Layer 1: K=512, 16 k-steps; B quad-buffered; gathers interleaved
    short8 bq[4][2];
#pragma unroll
    for (int s = 0; s < 4; ++s)
#pragma unroll
      for (int j = 0; j < 2; ++j)
        bq[s][j] = B1[(s * 256 + w * 32 + j * 16 + lm) * 4 + lq];

#pragma unroll
    for (int s = 0; s < 16; ++s) {
      if ((s & 1) == 0 && pre) gatherTo(An, n1, s >> 1);
      short8 af[4];
#pragma unroll
      for (int ii = 0; ii < 4; ++ii)
        af[ii] = ((const short8*)Ac)[(s * 4 + ii) * 64 + lane];
#pragma unroll
      for (int ii = 0; ii < 4; ++ii)
#pragma unroll
        for (int j = 0; j < 2; ++j)
          acc[ii][j] = __builtin_amdgcn_mfma_f32_16x16x32_bf16(af[ii], bq[s & 3][j], acc[ii][j], 0, 0, 0);
      if (s < 12)
#pragma unroll
        for (int j = 0; j < 2; ++j)
          bq[s & 3][j] = B1[((s + 4) * 256 + w * 32 + j * 16 + lm) * 4 + lq];
    }
    __syncthreads();   // L1 A-reads done; residual i+1 gathers drain here

    // ---- Epilogue 1: relu -> X (C/D map: col=lane&15, row=quad*4+reg)
#pragma unroll
    for (int ii = 0; ii < 4; ++ii) {
      int row0 = ii * 16 + lq * 4;
#pragma unroll
      for (int j = 0; j < 2; ++j) {
        int col = w * 32 + j * 16 + lm;
        int c8 = col >> 3, ce = col & 7;
#pragma unroll
        for (int rg = 0; rg < 4; ++rg) {
          int row = row0 + rg;
          float v = acc[ii][j][rg];
          v = v > 0.0f ? v : 0.0f;
          X[row * 256 + (((c8 ^ (row & 7)) << 3) | ce)] = f2bf(v);
        }
      }
    }
    // rotate index pipeline (i+3 two-ahead)
#pragma unroll
    for (int ii = 0; ii < 4; ++ii) n1[ii] = n2[ii];
    loadIdx(n2, (i + 3) <= last ? (i + 3) : last);

#pragma unroll
    for (int ii = 0; ii < 4; ++ii)
#pragma unroll
      for (int j = 0; j < 2; ++j) acc[ii][j] = (floatx4)(0.0f);
    __syncthreads();   // X visible

    // ---- Layer 2: K=256, 8 k-steps; A from X (swizzled b128); B double-buffered
    short8 bb[2][2];
#pragma unroll
    for (int s = 0; s < 2; ++s)
#pragma unroll
      for (int j = 0; j < 2; ++j)
        bb[s][j] = B2[(s * 256 + w * 32 + j * 16 + lm) * 4 + lq];
#pragma unroll
    for (int s = 0; s < 8; ++s) {
      short8 af[4];
#pragma unroll
      for (int ii = 0; ii < 4; ++ii) {
        int r = ii * 16 + lm, c8 = s * 4 + lq;
        af[ii] = *(const short8*)&X[r * 256 + ((c8 ^ (r & 7)) << 3)];
      }
#pragma unroll
      for (int ii = 0; ii < 4; ++ii)
#pragma unroll
        for (int j = 0; j < 2; ++j)
          acc[ii][j] = __builtin_amdgcn_mfma_f32_16x16x32_bf16(af[ii], bb[s & 1][j], acc[ii][j], 0, 0, 0);
      if (s < 6)
#pragma unroll
        for (int j = 0; j < 2; ++j)
          bb[s & 1][j] = B2[((s + 2) * 256 + w * 32 + j * 16 + lm) * 4 + lq];
    }
    __syncthreads();   // X reads done

    // ---- Epilogue 2: relu -> X in place
#pragma unroll
    for (int ii = 0; ii < 4; ++ii) {
      int row0 = ii * 16 + lq * 4;
#pragma unroll
      for (int j = 0; j < 2; ++j) {
        int col = w * 32 + j * 16 + lm;
        int c8 = col >> 3, ce = col & 7;
#pragma unroll
        for (int rg = 0; rg < 4; ++rg) {
          int row = row0 + rg;
          float v = acc[ii][j][rg];
          v = v > 0.0f ? v : 0.0f;
          X[row * 256 + (((c8 ^ (row & 7)) << 3) | ce)] = f2bf(v);
        }
      }
    }
    __syncthreads();

    // ---- Layer 3: out = X @ W3 (fp32 VALU; 8 threads/row)
    {
      int r = t >> 3, o = (t >> 2) & 1, q = t & 3;
      float s = 0.0f;
#pragma unroll
      for (int cc = 0; cc < 8; ++cc) {
        int c = q * 8 + cc;
        short8 xv = *(const short8*)&X[r * 256 + ((c ^ (r & 7)) << 3)];
#pragma unroll
        for (int e = 0; e < 8; ++e)
          s += bf2f((unsigned short)xv[e]) * w3s[((c << 3) + e) * 2 + o];
      }
      s += __shfl_xor(s, 1);
      s += __shfl_xor(s, 2);
      if (q == 0) out[(m0 + r) * 2 + o] = s;
    }
    __syncthreads();   // L3 X-reads done before next iter's gathers overwrite A[cur]
  }
}

// ---------------- Fallback (no workspace for bf16 table): R2-style fp32 gather ----
__global__ __launch_bounds__(256, 2)
void edge_mlp_fb(const float* __restrict__ h,
                 const int* __restrict__ dst,
                 const int* __restrict__ src,
                 const unsigned short* __restrict__ W1F,
                 const unsigned short* __restrict__ W2F,
                 const float* __restrict__ W3,
                 float* __restrict__ out) {
  __shared__ unsigned short A[64 * 512];
  __shared__ float w3s[512];
  __shared__ int ioff[128];
  unsigned short* X = A;

  const int t = threadIdx.x, lane = t & 63, w = t >> 6;
  const int lq = lane >> 4, lm = lane & 15;
  const int m0 = blockIdx.x * 64;

  if (t < 64) ioff[t] = dst[m0 + t];
  else if (t < 128) ioff[t] = src[m0 + t - 64];
  w3s[t] = W3[t];
  w3s[t + 256] = W3[t + 256];
  __syncthreads();
  {
    const int c = lane, half = (c >= 32) ? 64 : 0, cc = c & 31;
#pragma unroll
    for (int it = 0; it < 16; ++it) {
      int r = it * 4 + w;
      int node = ioff[half + r];
      const float4* h4 = (const float4*)h;
      float4 v0 = h4[node * 64 + cc * 2], v1 = h4[node * 64 + cc * 2 + 1];
      short8 v;
      v[0] = (short)f2bf(v0.x); v[1] = (short)f2bf(v0.y);
      v[2] = (short)f2bf(v0.z); v[3] = (short)f2bf(v0.w);
      v[4] = (short)f2bf(v1.x); v[5] = (short)f2bf(v1.y);
      v[6] = (short)f2bf(v1.z); v[7] = (short)f2bf(v1.w);
      *(short8*)&A[r * 512 + ((c ^ (r & 7)) << 3)] = v;
    }
  }
  floatx4 acc[4][4];
#pragma unroll
  for (int i = 0; i < 4; ++i)
#pragma unroll
    for (int j = 0; j < 4; ++j) acc[i][j] = (floatx4)(0.0f);
  __syncthreads();
  const short8* B1 = (const short8*)W1F;
  const short8* B2 = (const short8*)W2F;
#pragma unroll
  for (int k32 = 0; k32 < 16; ++k32) {
    short8 b[4], af[4];
#pragma unroll
    for (int jt = 0; jt < 4; ++jt)
      b[jt] = B1[(k32 * 256 + w * 64 + jt * 16 + lm) * 4 + lq];
#pragma unroll
    for (int i = 0; i < 4; ++i) {
      int r = i * 16 + lm, c = k32 * 4 + lq;
      af[i] = *(const short8*)&A[r * 512 + ((c ^ (r & 7)) << 3)];
    }
#pragma unroll
    for (int i = 0; i < 4; ++i)
#pragma unroll
      for (int j = 0; j < 4; ++j)
        acc[i][j] = __builtin_amdgcn_mfma_f32_16x16x32_bf16(af[i], b[j], acc[i][j], 0, 0, 0);
  }
  __syncthreads();
#pragma unroll
  for (int i = 0; i < 4; ++i) {
    int row0 = i * 16 + lq * 4;
#pragma unroll
    for (int j = 0; j < 4; ++j) {
      int col = w * 64 + j * 16 + lm, c8 = col >> 3, ce = col & 7;
#pragma unroll
      for (int rg = 0; rg < 4; ++rg) {
        int row = row0 + rg;
        float v = acc[i][j][rg];
        v = v > 0.0f ? v : 0.0f;
        X[row * 256 + (((c8 ^ (row & 7)) << 3) | ce)] = f2bf(v);
      }
    }
  }
#pragma unroll
  for (int i = 0; i < 4; ++i)
#pragma unroll
    for (int j = 0; j < 4; ++j) acc[i][j] = (floatx4)(0.0f);
  __syncthreads();
#pragma unroll
  for (int k32 = 0; k32 < 8; ++k32) {
    short8 b[4], af[4];
#pragma unroll
    for (int jt = 0; jt < 4; ++jt)
      b[jt] = B2[(k32 * 256 + w * 64 + jt * 16 + lm) * 4 + lq];
#pragma unroll
    for (int i = 0; i < 4; ++i) {
      int r = i * 16 + lm, c = k32 * 4 + lq;
      af[i] = *(const short8*)&X[r * 256 + ((c ^ (r & 7)) << 3)];
    }
#pragma unroll
    for (int i = 0; i < 4; ++i)
#pragma unroll
      for (int j = 0; j < 4; ++j)
        acc[i][j] = __builtin_amdgcn_mfma_f32_16x16x32_bf16(af[i], b[j], acc[i][j], 0, 0, 0);
  }
  __syncthreads();
#pragma unroll
  for (int i = 0; i < 4; ++i) {
    int row0 = i * 16 + lq * 4;
#pragma unroll
    for (int j = 0; j < 4; ++j) {
      int col = w * 64 + j * 16 + lm, c8 = col >> 3, ce = col & 7;
#pragma unroll
      for (int rg = 0; rg < 4; ++rg) {
        int row = row0 + rg;
        float v = acc[i][j][rg];
        v = v > 0.0f ? v : 0.0f;
        X[row * 256 + (((c8 ^ (row & 7)) << 3) | ce)] = f2bf(v);
      }
    }
  }
  __syncthreads();
  {
    int r = t >> 2, o = (t >> 1) & 1, hh = t & 1;
    float s = 0.0f;
#pragma unroll
    for (int it = 0; it < 16; ++it) {
      int c = hh * 16 + it;
      short8 xv = *(const short8*)&X[r * 256 + ((c ^ (r & 7)) << 3)];
#pragma unroll
      for (int e = 0; e < 8; ++e)
        s += bf2f((unsigned short)xv[e]) * w3s[((c << 3) + e) * 2 + o];
    }
    s += __shfl_xor(s, 1);
    if (hh == 0) out[(m0 + r) * 2 + o] = s;
  }
}

extern "C" void kernel_launch(void* const* d_in, const int* in_sizes, int n_in,
                              void* d_out, int out_size, void* d_ws, size_t ws_size,
                              hipStream_t stream) {
  const float* h   = (const float*)d_in[0];
  const int*   dst = (const int*)d_in[1];
  const int*   src = (const int*)d_in[2];
  const float* W1  = (const float*)d_in[3];
  const float* W2  = (const float*)d_in[4];
  const float* W3  = (const float*)d_in[5];
  float* out = (float*)d_out;

  const int h_elems = in_sizes[0];
  const int n_pairs = in_sizes[1];
  const int ntiles  = n_pairs / 64;

  const size_t hbf_elems = (size_t)h_elems;
  const bool use_hbf = ws_size >= (hbf_elems + 131072 + 65536) * sizeof(unsigned short);

  unsigned short* HBF = (unsigned short*)d_ws;
  unsigned short* W1F = use_hbf ? HBF + hbf_elems : (unsigned short*)d_ws;
  unsigned short* W2F = W1F + 131072;

  wfrag_kernel<<<512, 256, 0, stream>>>(W1, W1F, 131072);
  wfrag_kernel<<<256, 256, 0, stream>>>(W2, W2F, 65536);

  if (use_hbf) {
    int total8 = h_elems / 8;
    hcvt_kernel<<<(total8 + 255) / 256, 256, 0, stream>>>(h, HBF, total8);
    int grid = ntiles < 256 ? ntiles : 256;   // persistent, 1 block/CU
    edge_mlp_pipe<<<grid, 512, 0, stream>>>(HBF, dst, src, W1F, W2F, W3, out, ntiles);
  } else {
    edge_mlp_fb<<<ntiles, 256, 0, stream>>>(h, dst, src, W1F, W2F, W3, out);
  }
}

// Round 5
// 576.829 us; speedup vs baseline: 2.0577x; 1.6126x over previous
//
#include <hip/hip_runtime.h>
#include <stdint.h>

typedef __attribute__((ext_vector_type(8))) short short8;
typedef __attribute__((ext_vector_type(4))) float floatx4;

#define BSHIFT 5   // 32 nodes per bucket

__device__ __forceinline__ unsigned short f2bf(float x) {
  unsigned int u = __float_as_uint(x);
  u += 0x7fffu + ((u >> 16) & 1u);   // RNE
  return (unsigned short)(u >> 16);
}
__device__ __forceinline__ float bf2f(unsigned short b) {
  return __uint_as_float(((unsigned int)b) << 16);
}

// h fp32 [N,256] -> bf16 [N,256] row-major
__global__ void hcvt_kernel(const float* __restrict__ h,
                            unsigned short* __restrict__ o, int total8) {
  int u = blockIdx.x * 256 + threadIdx.x;
  if (u >= total8) return;
  const float4* h4 = (const float4*)h;
  float4 v0 = h4[u * 2], v1 = h4[u * 2 + 1];
  short8 s;
  s[0] = (short)f2bf(v0.x); s[1] = (short)f2bf(v0.y);
  s[2] = (short)f2bf(v0.z); s[3] = (short)f2bf(v0.w);
  s[4] = (short)f2bf(v1.x); s[5] = (short)f2bf(v1.y);
  s[6] = (short)f2bf(v1.z); s[7] = (short)f2bf(v1.w);
  ((short8*)o)[u] = s;
}

// W [K][256] fp32 -> fragment-major bf16: u=((k32*256+n)*4+kq)*8+j holds W[k32*32+kq*8+j][n]
__global__ void wfrag_kernel(const float* __restrict__ W,
                             unsigned short* __restrict__ out, int total) {
  int u = blockIdx.x * 256 + threadIdx.x;
  if (u >= total) return;
  int j   = u & 7;
  int kq  = (u >> 3) & 3;
  int n   = (u >> 5) & 255;
  int k32 = u >> 13;
  int k   = k32 * 32 + kq * 8 + j;
  out[u] = f2bf(W[k * 256 + n]);
}

// ---- counting sort of edge ids by dst bucket ----
__global__ void hist_kernel(const int* __restrict__ dst, int* __restrict__ hist, int P) {
  int e = blockIdx.x * 256 + threadIdx.x;
  if (e < P) atomicAdd(&hist[dst[e] >> BSHIFT], 1);
}
__global__ void scan_kernel(const int* __restrict__ hist, int* __restrict__ cursor, int nb) {
  __shared__ int part[256];
  int t = threadIdx.x;
  int chunk = (nb + 255) / 256;
  int b0 = t * chunk;
  int s = 0;
  for (int j = 0; j < chunk; ++j) { int b = b0 + j; if (b < nb) s += hist[b]; }
  part[t] = s;
  __syncthreads();
  if (t == 0) { int acc = 0; for (int i = 0; i < 256; ++i) { int v = part[i]; part[i] = acc; acc += v; } }
  __syncthreads();
  int acc = part[t];
  for (int j = 0; j < chunk; ++j) { int b = b0 + j; if (b < nb) { cursor[b] = acc; acc += hist[b]; } }
}
__global__ void scatter_kernel(const int* __restrict__ dst, int* __restrict__ cursor,
                               int* __restrict__ perm, int P) {
  int e = blockIdx.x * 256 + threadIdx.x;
  if (e < P) { int pos = atomicAdd(&cursor[dst[e] >> BSHIFT], 1); perm[pos] = e; }
}

// ---- main kernel: R2 structure, optional permuted edge order ----
// LDS: A 64x512 bf16 (64 KB, X overlays), w3 2 KB, ioff+eidx ~0.8 KB -> 2 blocks/CU
template <bool SORTED>
__global__ __launch_bounds__(256, 2)
void edge_mlp2(const unsigned short* __restrict__ hbf,
               const int* __restrict__ dst,
               const int* __restrict__ src,
               const int* __restrict__ perm,
               const unsigned short* __restrict__ W1F,
               const unsigned short* __restrict__ W2F,
               const float* __restrict__ W3,
               float* __restrict__ out) {
  __shared__ unsigned short A[64 * 512];
  __shared__ float w3s[512];
  __shared__ int ioff[128];
  __shared__ int eidx[64];
  unsigned short* X = A;  // overlay, row stride 256

  const int t = threadIdx.x, lane = t & 63, w = t >> 6;
  const int lq = lane >> 4, lm = lane & 15;
  const int m0 = blockIdx.x * 64;

  if (t < 64) {
    int e = SORTED ? perm[m0 + t] : (m0 + t);
    eidx[t] = e;
    ioff[t] = dst[e];
  } else if (t < 128) {
    int e = SORTED ? perm[m0 + t - 64] : (m0 + t - 64);
    ioff[t] = src[e];
  }
  w3s[t] = W3[t];
  w3s[t + 256] = W3[t + 256];
  __syncthreads();

  // gather: wave-uniform row -> two 512 B coalesced segments per iteration
  {
    const int c = lane, half = (c >= 32) ? 64 : 0, cc = c & 31;
#pragma unroll
    for (int it = 0; it < 16; ++it) {
      int r = it * 4 + w;
      int node = ioff[half + r];
      short8 v = ((const short8*)hbf)[node * 32 + cc];
      *(short8*)&A[r * 512 + ((c ^ (r & 7)) << 3)] = v;
    }
  }

  floatx4 acc[4][4];
#pragma unroll
  for (int i = 0; i < 4; ++i)
#pragma unroll
    for (int j = 0; j < 4; ++j) acc[i][j] = (floatx4)(0.0f);
  __syncthreads();

  const short8* B1 = (const short8*)W1F;
  const short8* B2 = (const short8*)W2F;

  // Layer 1: K=512, 16 k-steps, B from global (L2), software-pipelined
  {
    auto loadB = [&](short8* b, int k32) {
#pragma unroll
      for (int jt = 0; jt < 4; ++jt)
        b[jt] = B1[(k32 * 256 + w * 64 + jt * 16 + lm) * 4 + lq];
    };
    auto step = [&](int k32, const short8* b) {
      short8 af[4];
#pragma unroll
      for (int i = 0; i < 4; ++i) {
        int r = i * 16 + lm, c = k32 * 4 + lq;
        af[i] = *(const short8*)&A[r * 512 + ((c ^ (r & 7)) << 3)];
      }
#pragma unroll
      for (int i = 0; i < 4; ++i)
#pragma unroll
        for (int j = 0; j < 4; ++j)
          acc[i][j] = __builtin_amdgcn_mfma_f32_16x16x32_bf16(af[i], b[j], acc[i][j], 0, 0, 0);
    };
    short8 b0[4], b1[4];
    loadB(b0, 0);
#pragma unroll
    for (int k2 = 0; k2 < 8; ++k2) {
      loadB(b1, k2 * 2 + 1);
      step(k2 * 2, b0);
      loadB(b0, (k2 * 2 + 2) & 15);
      step(k2 * 2 + 1, b1);
    }
  }
  __syncthreads();
  // Epilogue 1: relu -> X (C/D map: col=lane&15, row=quad*4+reg)
#pragma unroll
  for (int i = 0; i < 4; ++i) {
    int row0 = i * 16 + lq * 4;
#pragma unroll
    for (int j = 0; j < 4; ++j) {
      int col = w * 64 + j * 16 + lm, c8 = col >> 3, ce = col & 7;
#pragma unroll
      for (int rg = 0; rg < 4; ++rg) {
        int row = row0 + rg;
        float v = acc[i][j][rg];
        v = v > 0.0f ? v : 0.0f;
        X[row * 256 + (((c8 ^ (row & 7)) << 3) | ce)] = f2bf(v);
      }
    }
  }
#pragma unroll
  for (int i = 0; i < 4; ++i)
#pragma unroll
    for (int j = 0; j < 4; ++j) acc[i][j] = (floatx4)(0.0f);
  __syncthreads();

  // Layer 2: K=256, 8 k-steps
  {
    auto loadB = [&](short8* b, int k32) {
#pragma unroll
      for (int jt = 0; jt < 4; ++jt)
        b[jt] = B2[(k32 * 256 + w * 64 + jt * 16 + lm) * 4 + lq];
    };
    auto step = [&](int k32, const short8* b) {
      short8 af[4];
#pragma unroll
      for (int i = 0; i < 4; ++i) {
        int r = i * 16 + lm, c = k32 * 4 + lq;
        af[i] = *(const short8*)&X[r * 256 + ((c ^ (r & 7)) << 3)];
      }
#pragma unroll
      for (int i = 0; i < 4; ++i)
#pragma unroll
        for (int j = 0; j < 4; ++j)
          acc[i][j] = __builtin_amdgcn_mfma_f32_16x16x32_bf16(af[i], b[j], acc[i][j], 0, 0, 0);
    };
    short8 b0[4], b1[4];
    loadB(b0, 0);
#pragma unroll
    for (int k2 = 0; k2 < 4; ++k2) {
      loadB(b1, k2 * 2 + 1);
      step(k2 * 2, b0);
      loadB(b0, (k2 * 2 + 2) & 7);
      step(k2 * 2 + 1, b1);
    }
  }
  __syncthreads();
  // Epilogue 2: relu -> X
#pragma unroll
  for (int i = 0; i < 4; ++i) {
    int row0 = i * 16 + lq * 4;
#pragma unroll
    for (int j = 0; j < 4; ++j) {
      int col = w * 64 + j * 16 + lm, c8 = col >> 3, ce = col & 7;
#pragma unroll
      for (int rg = 0; rg < 4; ++rg) {
        int row = row0 + rg;
        float v = acc[i][j][rg];
        v = v > 0.0f ? v : 0.0f;
        X[row * 256 + (((c8 ^ (row & 7)) << 3) | ce)] = f2bf(v);
      }
    }
  }
  __syncthreads();

  // Layer 3: out[e] = X @ W3 (fp32 VALU, N=2), scattered to original edge ids
  {
    int r = t >> 2, o = (t >> 1) & 1, hh = t & 1;
    float s = 0.0f;
#pragma unroll
    for (int it = 0; it < 16; ++it) {
      int c = hh * 16 + it;
      short8 xv = *(const short8*)&X[r * 256 + ((c ^ (r & 7)) << 3)];
#pragma unroll
      for (int e = 0; e < 8; ++e)
        s += bf2f((unsigned short)xv[e]) * w3s[((c << 3) + e) * 2 + o];
    }
    s += __shfl_xor(s, 1);
    if (hh == 0) {
      int e = SORTED ? eidx[r] : (m0 + r);
      out[e * 2 + o] = s;
    }
  }
}

// ---- fp32-gather fallback (tiny workspace) ----
__global__ __launch_bounds__(256, 2)
void edge_mlp_fb(const float* __restrict__ h,
                 const int* __restrict__ dst,
                 const int* __restrict__ src,
                 const unsigned short* __restrict__ W1F,
                 const unsigned short* __restrict__ W2F,
                 const float* __restrict__ W3,
                 float* __restrict__ out) {
  __shared__ unsigned short A[64 * 512];
  __shared__ float w3s[512];
  __shared__ int ioff[128];
  unsigned short* X = A;
  const int t = threadIdx.x, lane = t & 63, w = t >> 6;
  const int lq = lane >> 4, lm = lane & 15;
  const int m0 = blockIdx.x * 64;
  if (t < 64) ioff[t] = dst[m0 + t];
  else if (t < 128) ioff[t] = src[m0 + t - 64];
  w3s[t] = W3[t];
  w3s[t + 256] = W3[t + 256];
  __syncthreads();
  {
    const int c = lane, half = (c >= 32) ? 64 : 0, cc = c & 31;
#pragma unroll
    for (int it = 0; it < 16; ++it) {
      int r = it * 4 + w;
      int node = ioff[half + r];
      const float4* h4 = (const float4*)h;
      float4 v0 = h4[node * 64 + cc * 2], v1 = h4[node * 64 + cc * 2 + 1];
      short8 v;
      v[0] = (short)f2bf(v0.x); v[1] = (short)f2bf(v0.y);
      v[2] = (short)f2bf(v0.z); v[3] = (short)f2bf(v0.w);
      v[4] = (short)f2bf(v1.x); v[5] = (short)f2bf(v1.y);
      v[6] = (short)f2bf(v1.z); v[7] = (short)f2bf(v1.w);
      *(short8*)&A[r * 512 + ((c ^ (r & 7)) << 3)] = v;
    }
  }
  floatx4 acc[4][4];
#pragma unroll
  for (int i = 0; i < 4; ++i)
#pragma unroll
    for (int j = 0; j < 4; ++j) acc[i][j] = (floatx4)(0.0f);
  __syncthreads();
  const short8* B1 = (const short8*)W1F;
  const short8* B2 = (const short8*)W2F;
#pragma unroll
  for (int k32 = 0; k32 < 16; ++k32) {
    short8 b[4], af[4];
#pragma unroll
    for (int jt = 0; jt < 4; ++jt)
      b[jt] = B1[(k32 * 256 + w * 64 + jt * 16 + lm) * 4 + lq];
#pragma unroll
    for (int i = 0; i < 4; ++i) {
      int r = i * 16 + lm, c = k32 * 4 + lq;
      af[i] = *(const short8*)&A[r * 512 + ((c ^ (r & 7)) << 3)];
    }
#pragma unroll
    for (int i = 0; i < 4; ++i)
#pragma unroll
      for (int j = 0; j < 4; ++j)
        acc[i][j] = __builtin_amdgcn_mfma_f32_16x16x32_bf16(af[i], b[j], acc[i][j], 0, 0, 0);
  }
  __syncthreads();
#pragma unroll
  for (int i = 0; i < 4; ++i) {
    int row0 = i * 16 + lq * 4;
#pragma unroll
    for (int j = 0; j < 4; ++j) {
      int col = w * 64 + j * 16 + lm, c8 = col >> 3, ce = col & 7;
#pragma unroll
      for (int rg = 0; rg < 4; ++rg) {
        int row = row0 + rg;
        float v = acc[i][j][rg];
        v = v > 0.0f ? v : 0.0f;
        X[row * 256 + (((c8 ^ (row & 7)) << 3) | ce)] = f2bf(v);
      }
    }
  }
#pragma unroll
  for (int i = 0; i < 4; ++i)
#pragma unroll
    for (int j = 0; j < 4; ++j) acc[i][j] = (floatx4)(0.0f);
  __syncthreads();
#pragma unroll
  for (int k32 = 0; k32 < 8; ++k32) {
    short8 b[4], af[4];
#pragma unroll
    for (int jt = 0; jt < 4; ++jt)
      b[jt] = B2[(k32 * 256 + w * 64 + jt * 16 + lm) * 4 + lq];
#pragma unroll
    for (int i = 0; i < 4; ++i) {
      int r = i * 16 + lm, c = k32 * 4 + lq;
      af[i] = *(const short8*)&X[r * 256 + ((c ^ (r & 7)) << 3)];
    }
#pragma unroll
    for (int i = 0; i < 4; ++i)
#pragma unroll
      for (int j = 0; j < 4; ++j)
        acc[i][j] = __builtin_amdgcn_mfma_f32_16x16x32_bf16(af[i], b[j], acc[i][j], 0, 0, 0);
  }
  __syncthreads();
#pragma unroll
  for (int i = 0; i < 4; ++i) {
    int row0 = i * 16 + lq * 4;
#pragma unroll
    for (int j = 0; j < 4; ++j) {
      int col = w * 64 + j * 16 + lm, c8 = col >> 3, ce = col & 7;
#pragma unroll
      for (int rg = 0; rg < 4; ++rg) {
        int row = row0 + rg;
        float v = acc[i][j][rg];
        v = v > 0.0f ? v : 0.0f;
        X[row * 256 + (((c8 ^ (row & 7)) << 3) | ce)] = f2bf(v);
      }
    }
  }
  __syncthreads();
  {
    int r = t >> 2, o = (t >> 1) & 1, hh = t & 1;
    float s = 0.0f;
#pragma unroll
    for (int it = 0; it < 16; ++it) {
      int c = hh * 16 + it;
      short8 xv = *(const short8*)&X[r * 256 + ((c ^ (r & 7)) << 3)];
#pragma unroll
      for (int e = 0; e < 8; ++e)
        s += bf2f((unsigned short)xv[e]) * w3s[((c << 3) + e) * 2 + o];
    }
    s += __shfl_xor(s, 1);
    if (hh == 0) out[(m0 + r) * 2 + o] = s;
  }
}

extern "C" void kernel_launch(void* const* d_in, const int* in_sizes, int n_in,
                              void* d_out, int out_size, void* d_ws, size_t ws_size,
                              hipStream_t stream) {
  const float* h   = (const float*)d_in[0];
  const int*   dst = (const int*)d_in[1];
  const int*   src = (const int*)d_in[2];
  const float* W1  = (const float*)d_in[3];
  const float* W2  = (const float*)d_in[4];
  const float* W3  = (const float*)d_in[5];
  float* out = (float*)d_out;

  const int h_elems = in_sizes[0];
  const int n_pairs = in_sizes[1];
  const int ntiles  = n_pairs / 64;
  const int nnodes  = h_elems / 256;
  const int nb      = (nnodes >> BSHIFT) + 1;

  // ws layout: HBF | W1F | W2F | hist | cursor | perm
  size_t off = 0;
  unsigned short* HBF = (unsigned short*)d_ws;           off += (size_t)h_elems * 2;
  unsigned short* W1F = (unsigned short*)((char*)d_ws + off); off += 131072 * 2;
  unsigned short* W2F = (unsigned short*)((char*)d_ws + off); off += 65536 * 2;
  int* hist   = (int*)((char*)d_ws + off); off += (size_t)nb * 4;
  int* cursor = (int*)((char*)d_ws + off); off += (size_t)nb * 4;
  int* perm   = (int*)((char*)d_ws + off); off += (size_t)n_pairs * 4;

  const bool ws_full = ws_size >= off;
  const bool ws_hbf  = ws_size >= ((size_t)h_elems + 131072 + 65536) * 2;

  if (ws_full) {
    wfrag_kernel<<<512, 256, 0, stream>>>(W1, W1F, 131072);
    wfrag_kernel<<<256, 256, 0, stream>>>(W2, W2F, 65536);
    int total8 = h_elems / 8;
    hcvt_kernel<<<(total8 + 255) / 256, 256, 0, stream>>>(h, HBF, total8);
    hipMemsetAsync(hist, 0, (size_t)nb * 4, stream);
    hist_kernel<<<(n_pairs + 255) / 256, 256, 0, stream>>>(dst, hist, n_pairs);
    scan_kernel<<<1, 256, 0, stream>>>(hist, cursor, nb);
    scatter_kernel<<<(n_pairs + 255) / 256, 256, 0, stream>>>(dst, cursor, perm, n_pairs);
    edge_mlp2<true><<<ntiles, 256, 0, stream>>>(HBF, dst, src, perm, W1F, W2F, W3, out);
  } else if (ws_hbf) {
    unsigned short* W1Fb = HBF + h_elems;
    unsigned short* W2Fb = W1Fb + 131072;
    wfrag_kernel<<<512, 256, 0, stream>>>(W1, W1Fb, 131072);
    wfrag_kernel<<<256, 256, 0, stream>>>(W2, W2Fb, 65536);
    int total8 = h_elems / 8;
    hcvt_kernel<<<(total8 + 255) / 256, 256, 0, stream>>>(h, HBF, total8);
    edge_mlp2<false><<<ntiles, 256, 0, stream>>>(HBF, dst, src, nullptr, W1Fb, W2Fb, W3, out);
  } else {
    unsigned short* W1Fb = (unsigned short*)d_ws;
    unsigned short* W2Fb = W1Fb + 131072;
    wfrag_kernel<<<512, 256, 0, stream>>>(W1, W1Fb, 131072);
    wfrag_kernel<<<256, 256, 0, stream>>>(W2, W2Fb, 65536);
    edge_mlp_fb<<<ntiles, 256, 0, stream>>>(h, dst, src, W1Fb, W2Fb, W3, out);
  }
}

// Round 6
// 416.261 us; speedup vs baseline: 2.8514x; 1.3857x over previous
//
#include <hip/hip_runtime.h>
#include <stdint.h>

typedef __attribute__((ext_vector_type(8))) short short8;
typedef __attribute__((ext_vector_type(4))) float floatx4;

__device__ __forceinline__ unsigned short f2bf(float x) {
  unsigned int u = __float_as_uint(x);
  u += 0x7fffu + ((u >> 16) & 1u);   // RNE
  return (unsigned short)(u >> 16);
}
__device__ __forceinline__ float bf2f(unsigned short b) {
  return __uint_as_float(((unsigned int)b) << 16);
}

// h fp32 [N,256] -> bf16 [N,256] row-major
__global__ void hcvt_kernel(const float* __restrict__ h,
                            unsigned short* __restrict__ o, int total8) {
  int u = blockIdx.x * 256 + threadIdx.x;
  if (u >= total8) return;
  const float4* h4 = (const float4*)h;
  float4 v0 = h4[u * 2], v1 = h4[u * 2 + 1];
  short8 s;
  s[0] = (short)f2bf(v0.x); s[1] = (short)f2bf(v0.y);
  s[2] = (short)f2bf(v0.z); s[3] = (short)f2bf(v0.w);
  s[4] = (short)f2bf(v1.x); s[5] = (short)f2bf(v1.y);
  s[6] = (short)f2bf(v1.z); s[7] = (short)f2bf(v1.w);
  ((short8*)o)[u] = s;
}

// W [K][256] fp32 -> fragment-major bf16: u=((k32*256+n)*4+kq)*8+j holds W[k32*32+kq*8+j][n]
__global__ void wfrag_kernel(const float* __restrict__ W,
                             unsigned short* __restrict__ out, int total) {
  int u = blockIdx.x * 256 + threadIdx.x;
  if (u >= total) return;
  int j   = u & 7;
  int kq  = (u >> 3) & 3;
  int n   = (u >> 5) & 255;
  int k32 = u >> 13;
  int k   = k32 * 32 + kq * 8 + j;
  out[u] = f2bf(W[k * 256 + n]);
}

// ---- main kernel: R2 structure + deep pipelining ----
// LDS: A 64x512 bf16 (64 KB, X overlays), w3 2 KB, ioff 512 B -> 2 blocks/CU.
// VGPR budget 256 (2 waves/EU): gather 16x8 regs fully in flight (dies before L1);
// B-ring depth 4 (128 regs) gives ~310 cyc of load lookahead per k-step.
__global__ __launch_bounds__(256, 2)
void edge_mlp2(const unsigned short* __restrict__ hbf,
               const int* __restrict__ dst,
               const int* __restrict__ src,
               const unsigned short* __restrict__ W1F,
               const unsigned short* __restrict__ W2F,
               const float* __restrict__ W3,
               float* __restrict__ out) {
  __shared__ unsigned short A[64 * 512];
  __shared__ float w3s[512];
  __shared__ int ioff[128];
  unsigned short* X = A;  // overlay, row stride 256

  const int t = threadIdx.x, lane = t & 63, w = t >> 6;
  const int lq = lane >> 4, lm = lane & 15;
  const int m0 = blockIdx.x * 64;

  if (t < 64)       ioff[t] = dst[m0 + t];
  else if (t < 128) ioff[t] = src[m0 + t - 64];
  w3s[t] = W3[t];
  w3s[t + 256] = W3[t + 256];
  __syncthreads();

  // ---- Gather: all 16 wave-coalesced 1 KB loads in flight, then LDS writes
  {
    const int c = lane, half = (c >= 32) ? 64 : 0, cc = c & 31;
    short8 g[16];
#pragma unroll
    for (int it = 0; it < 16; ++it) {
      int node = ioff[half + it * 4 + w];
      g[it] = ((const short8*)hbf)[node * 32 + cc];
    }
#pragma unroll
    for (int it = 0; it < 16; ++it) {
      int r = it * 4 + w;
      *(short8*)&A[r * 512 + ((c ^ (r & 7)) << 3)] = g[it];
    }
  }

  floatx4 acc[4][4];
#pragma unroll
  for (int i = 0; i < 4; ++i)
#pragma unroll
    for (int j = 0; j < 4; ++j) acc[i][j] = (floatx4)(0.0f);
  __syncthreads();

  const short8* B1 = (const short8*)W1F;
  const short8* B2 = (const short8*)W2F;

  // ---- Layer 1: K=512, 16 k-steps, B-ring depth 4
  {
    short8 bq[4][4];
#pragma unroll
    for (int s = 0; s < 4; ++s)
#pragma unroll
      for (int jt = 0; jt < 4; ++jt)
        bq[s][jt] = B1[(s * 256 + w * 64 + jt * 16 + lm) * 4 + lq];

#pragma unroll
    for (int s = 0; s < 16; ++s) {
#pragma unroll
      for (int i = 0; i < 4; ++i) {
        int r = i * 16 + lm, cch = s * 4 + lq;
        short8 af = *(const short8*)&A[r * 512 + ((cch ^ (r & 7)) << 3)];
#pragma unroll
        for (int j = 0; j < 4; ++j)
          acc[i][j] = __builtin_amdgcn_mfma_f32_16x16x32_bf16(af, bq[s & 3][j], acc[i][j], 0, 0, 0);
      }
      if (s < 12)
#pragma unroll
        for (int jt = 0; jt < 4; ++jt)
          bq[s & 3][jt] = B1[((s + 4) * 256 + w * 64 + jt * 16 + lm) * 4 + lq];
    }
  }
  __syncthreads();
  // Epilogue 1: relu -> X (C/D map: col=lane&15, row=quad*4+reg)
#pragma unroll
  for (int i = 0; i < 4; ++i) {
    int row0 = i * 16 + lq * 4;
#pragma unroll
    for (int j = 0; j < 4; ++j) {
      int col = w * 64 + j * 16 + lm, c8 = col >> 3, ce = col & 7;
#pragma unroll
      for (int rg = 0; rg < 4; ++rg) {
        int row = row0 + rg;
        float v = acc[i][j][rg];
        v = v > 0.0f ? v : 0.0f;
        X[row * 256 + (((c8 ^ (row & 7)) << 3) | ce)] = f2bf(v);
      }
    }
  }
#pragma unroll
  for (int i = 0; i < 4; ++i)
#pragma unroll
    for (int j = 0; j < 4; ++j) acc[i][j] = (floatx4)(0.0f);
  __syncthreads();

  // ---- Layer 2: K=256, 8 k-steps, B-ring depth 4
  {
    short8 bq[4][4];
#pragma unroll
    for (int s = 0; s < 4; ++s)
#pragma unroll
      for (int jt = 0; jt < 4; ++jt)
        bq[s][jt] = B2[(s * 256 + w * 64 + jt * 16 + lm) * 4 + lq];

#pragma unroll
    for (int s = 0; s < 8; ++s) {
#pragma unroll
      for (int i = 0; i < 4; ++i) {
        int r = i * 16 + lm, cch = s * 4 + lq;
        short8 af = *(const short8*)&X[r * 256 + ((cch ^ (r & 7)) << 3)];
#pragma unroll
        for (int j = 0; j < 4; ++j)
          acc[i][j] = __builtin_amdgcn_mfma_f32_16x16x32_bf16(af, bq[s & 3][j], acc[i][j], 0, 0, 0);
      }
      if (s < 4)
#pragma unroll
        for (int jt = 0; jt < 4; ++jt)
          bq[s & 3][jt] = B2[((s + 4) * 256 + w * 64 + jt * 16 + lm) * 4 + lq];
    }
  }
  __syncthreads();
  // Epilogue 2: relu -> X
#pragma unroll
  for (int i = 0; i < 4; ++i) {
    int row0 = i * 16 + lq * 4;
#pragma unroll
    for (int j = 0; j < 4; ++j) {
      int col = w * 64 + j * 16 + lm, c8 = col >> 3, ce = col & 7;
#pragma unroll
      for (int rg = 0; rg < 4; ++rg) {
        int row = row0 + rg;
        float v = acc[i][j][rg];
        v = v > 0.0f ? v : 0.0f;
        X[row * 256 + (((c8 ^ (row & 7)) << 3) | ce)] = f2bf(v);
      }
    }
  }
  __syncthreads();

  // ---- Layer 3: out = X @ W3 (fp32 VALU, N=2)
  {
    int r = t >> 2, o = (t >> 1) & 1, hh = t & 1;
    float s = 0.0f;
#pragma unroll
    for (int it = 0; it < 16; ++it) {
      int c = hh * 16 + it;
      short8 xv = *(const short8*)&X[r * 256 + ((c ^ (r & 7)) << 3)];
#pragma unroll
      for (int e = 0; e < 8; ++e)
        s += bf2f((unsigned short)xv[e]) * w3s[((c << 3) + e) * 2 + o];
    }
    s += __shfl_xor(s, 1);
    if (hh == 0) out[(m0 + r) * 2 + o] = s;
  }
}

// ---- fp32-gather fallback (tiny workspace) ----
__global__ __launch_bounds__(256, 2)
void edge_mlp_fb(const float* __restrict__ h,
                 const int* __restrict__ dst,
                 const int* __restrict__ src,
                 const unsigned short* __restrict__ W1F,
                 const unsigned short* __restrict__ W2F,
                 const float* __restrict__ W3,
                 float* __restrict__ out) {
  __shared__ unsigned short A[64 * 512];
  __shared__ float w3s[512];
  __shared__ int ioff[128];
  unsigned short* X = A;
  const int t = threadIdx.x, lane = t & 63, w = t >> 6;
  const int lq = lane >> 4, lm = lane & 15;
  const int m0 = blockIdx.x * 64;
  if (t < 64) ioff[t] = dst[m0 + t];
  else if (t < 128) ioff[t] = src[m0 + t - 64];
  w3s[t] = W3[t];
  w3s[t + 256] = W3[t + 256];
  __syncthreads();
  {
    const int c = lane, half = (c >= 32) ? 64 : 0, cc = c & 31;
#pragma unroll
    for (int it = 0; it < 16; ++it) {
      int r = it * 4 + w;
      int node = ioff[half + r];
      const float4* h4 = (const float4*)h;
      float4 v0 = h4[node * 64 + cc * 2], v1 = h4[node * 64 + cc * 2 + 1];
      short8 v;
      v[0] = (short)f2bf(v0.x); v[1] = (short)f2bf(v0.y);
      v[2] = (short)f2bf(v0.z); v[3] = (short)f2bf(v0.w);
      v[4] = (short)f2bf(v1.x); v[5] = (short)f2bf(v1.y);
      v[6] = (short)f2bf(v1.z); v[7] = (short)f2bf(v1.w);
      *(short8*)&A[r * 512 + ((c ^ (r & 7)) << 3)] = v;
    }
  }
  floatx4 acc[4][4];
#pragma unroll
  for (int i = 0; i < 4; ++i)
#pragma unroll
    for (int j = 0; j < 4; ++j) acc[i][j] = (floatx4)(0.0f);
  __syncthreads();
  const short8* B1 = (const short8*)W1F;
  const short8* B2 = (const short8*)W2F;
#pragma unroll
  for (int k32 = 0; k32 < 16; ++k32) {
    short8 b[4], af[4];
#pragma unroll
    for (int jt = 0; jt < 4; ++jt)
      b[jt] = B1[(k32 * 256 + w * 64 + jt * 16 + lm) * 4 + lq];
#pragma unroll
    for (int i = 0; i < 4; ++i) {
      int r = i * 16 + lm, c = k32 * 4 + lq;
      af[i] = *(const short8*)&A[r * 512 + ((c ^ (r & 7)) << 3)];
    }
#pragma unroll
    for (int i = 0; i < 4; ++i)
#pragma unroll
      for (int j = 0; j < 4; ++j)
        acc[i][j] = __builtin_amdgcn_mfma_f32_16x16x32_bf16(af[i], b[j], acc[i][j], 0, 0, 0);
  }
  __syncthreads();
#pragma unroll
  for (int i = 0; i < 4; ++i) {
    int row0 = i * 16 + lq * 4;
#pragma unroll
    for (int j = 0; j < 4; ++j) {
      int col = w * 64 + j * 16 + lm, c8 = col >> 3, ce = col & 7;
#pragma unroll
      for (int rg = 0; rg < 4; ++rg) {
        int row = row0 + rg;
        float v = acc[i][j][rg];
        v = v > 0.0f ? v : 0.0f;
        X[row * 256 + (((c8 ^ (row & 7)) << 3) | ce)] = f2bf(v);
      }
    }
  }
#pragma unroll
  for (int i = 0; i < 4; ++i)
#pragma unroll
    for (int j = 0; j < 4; ++j) acc[i][j] = (floatx4)(0.0f);
  __syncthreads();
#pragma unroll
  for (int k32 = 0; k32 < 8; ++k32) {
    short8 b[4], af[4];
#pragma unroll
    for (int jt = 0; jt < 4; ++jt)
      b[jt] = B2[(k32 * 256 + w * 64 + jt * 16 + lm) * 4 + lq];
#pragma unroll
    for (int i = 0; i < 4; ++i) {
      int r = i * 16 + lm, c = k32 * 4 + lq;
      af[i] = *(const short8*)&X[r * 256 + ((c ^ (r & 7)) << 3)];
    }
#pragma unroll
    for (int i = 0; i < 4; ++i)
#pragma unroll
      for (int j = 0; j < 4; ++j)
        acc[i][j] = __builtin_amdgcn_mfma_f32_16x16x32_bf16(af[i], b[j], acc[i][j], 0, 0, 0);
  }
  __syncthreads();
#pragma unroll
  for (int i = 0; i < 4; ++i) {
    int row0 = i * 16 + lq * 4;
#pragma unroll
    for (int j = 0; j < 4; ++j) {
      int col = w * 64 + j * 16 + lm, c8 = col >> 3, ce = col & 7;
#pragma unroll
      for (int rg = 0; rg < 4; ++rg) {
        int row = row0 + rg;
        float v = acc[i][j][rg];
        v = v > 0.0f ? v : 0.0f;
        X[row * 256 + (((c8 ^ (row & 7)) << 3) | ce)] = f2bf(v);
      }
    }
  }
  __syncthreads();
  {
    int r = t >> 2, o = (t >> 1) & 1, hh = t & 1;
    float s = 0.0f;
#pragma unroll
    for (int it = 0; it < 16; ++it) {
      int c = hh * 16 + it;
      short8 xv = *(const short8*)&X[r * 256 + ((c ^ (r & 7)) << 3)];
#pragma unroll
      for (int e = 0; e < 8; ++e)
        s += bf2f((unsigned short)xv[e]) * w3s[((c << 3) + e) * 2 + o];
    }
    s += __shfl_xor(s, 1);
    if (hh == 0) out[(m0 + r) * 2 + o] = s;
  }
}

extern "C" void kernel_launch(void* const* d_in, const int* in_sizes, int n_in,
                              void* d_out, int out_size, void* d_ws, size_t ws_size,
                              hipStream_t stream) {
  const float* h   = (const float*)d_in[0];
  const int*   dst = (const int*)d_in[1];
  const int*   src = (const int*)d_in[2];
  const float* W1  = (const float*)d_in[3];
  const float* W2  = (const float*)d_in[4];
  const float* W3  = (const float*)d_in[5];
  float* out = (float*)d_out;

  const int h_elems = in_sizes[0];
  const int n_pairs = in_sizes[1];
  const int ntiles  = n_pairs / 64;

  const size_t hbf_elems = (size_t)h_elems;
  const bool use_hbf = ws_size >= (hbf_elems + 131072 + 65536) * sizeof(unsigned short);

  unsigned short* HBF = (unsigned short*)d_ws;
  unsigned short* W1F = use_hbf ? HBF + hbf_elems : (unsigned short*)d_ws;
  unsigned short* W2F = W1F + 131072;

  wfrag_kernel<<<512, 256, 0, stream>>>(W1, W1F, 131072);
  wfrag_kernel<<<256, 256, 0, stream>>>(W2, W2F, 65536);

  if (use_hbf) {
    int total8 = h_elems / 8;
    hcvt_kernel<<<(total8 + 255) / 256, 256, 0, stream>>>(h, HBF, total8);
    edge_mlp2<<<ntiles, 256, 0, stream>>>(HBF, dst, src, W1F, W2F, W3, out);
  } else {
    edge_mlp_fb<<<ntiles, 256, 0, stream>>>(h, dst, src, W1F, W2F, W3, out);
  }
}

// Round 7
// 410.058 us; speedup vs baseline: 2.8945x; 1.0151x over previous
//
#include <hip/hip_runtime.h>
#include <stdint.h>

typedef __attribute__((ext_vector_type(8))) short short8;
typedef __attribute__((ext_vector_type(4))) short short4v;
typedef __attribute__((ext_vector_type(4))) float floatx4;

__device__ __forceinline__ unsigned short f2bf(float x) {
  unsigned int u = __float_as_uint(x);
  u += 0x7fffu + ((u >> 16) & 1u);   // RNE
  return (unsigned short)(u >> 16);
}
__device__ __forceinline__ float bf2f(unsigned short b) {
  return __uint_as_float(((unsigned int)b) << 16);
}
// row swizzle: 4 lq-groups of an epilogue write get 4 distinct bank-quads;
// fragment reads stay 2-way (free); gather writes stay bijective.
__device__ __forceinline__ int sw3(int r) { return (r & 7) ^ (((r >> 3) & 1) * 3); }

// ---- unified prologue: weight frags + h bf16 table, fully coalesced ----
// W1F/W2F B-frag layout: u=((k32*256+n)*4+kq)*8+j  holds W[k32*32+kq*8+j][n]
// W3F B-frag layout (N padded 2->16): u=(k32*64+L)*8+j holds W3[k32*32+(L>>4)*8+j][L&15] or 0
__global__ void prep_kernel(const float* __restrict__ h, const float* __restrict__ W1,
                            const float* __restrict__ W2, const float* __restrict__ W3,
                            unsigned short* __restrict__ HBF, unsigned short* __restrict__ W1F,
                            unsigned short* __restrict__ W2F, unsigned short* __restrict__ W3F,
                            int nh4) {
  const int t = threadIdx.x;
  int b = blockIdx.x;
  if (b < 512) {            // W1F: 131072 elems
    int u = b * 256 + t;
    int j = u & 7, kq = (u >> 3) & 3, n = (u >> 5) & 255, k32 = u >> 13;
    W1F[u] = f2bf(W1[(k32 * 32 + kq * 8 + j) * 256 + n]);
    return;
  }
  b -= 512;
  if (b < 256) {            // W2F: 65536 elems
    int u = b * 256 + t;
    int j = u & 7, kq = (u >> 3) & 3, n = (u >> 5) & 255, k32 = u >> 13;
    W2F[u] = f2bf(W2[(k32 * 32 + kq * 8 + j) * 256 + n]);
    return;
  }
  b -= 256;
  if (b < 16) {             // W3F: 4096 elems
    int u = b * 256 + t;
    int j = u & 7, L = (u >> 3) & 63, k32 = u >> 9;
    int n = L & 15, kq = L >> 4;
    W3F[u] = (n < 2) ? f2bf(W3[(k32 * 32 + kq * 8 + j) * 2 + n]) : (unsigned short)0;
    return;
  }
  b -= 16;
  int u = b * 256 + t;      // hcvt: one float4 -> short4 per thread (coalesced)
  if (u < nh4) {
    float4 v = ((const float4*)h)[u];
    short4v s;
    s[0] = (short)f2bf(v.x); s[1] = (short)f2bf(v.y);
    s[2] = (short)f2bf(v.z); s[3] = (short)f2bf(v.w);
    ((short4v*)HBF)[u] = s;
  }
}

// ---- main kernel: R6 structure + sw3 swizzle + MFMA layer-3 ----
// LDS: A 64x512 bf16 (64 KB; X overlays [0,32K), X2 [32K,64K)), ioff 512 B -> 2 blocks/CU
__global__ __launch_bounds__(256, 2)
void edge_mlp3(const unsigned short* __restrict__ hbf,
               const int* __restrict__ dst,
               const int* __restrict__ src,
               const unsigned short* __restrict__ W1F,
               const unsigned short* __restrict__ W2F,
               const unsigned short* __restrict__ W3F,
               float* __restrict__ out) {
  __shared__ unsigned short A[64 * 512];
  __shared__ int ioff[128];
  unsigned short* X  = A;            // [64][256] layer-1 output
  unsigned short* X2 = A + 16384;    // [64][256] layer-2 output

  const int t = threadIdx.x, lane = t & 63, w = t >> 6;
  const int lq = lane >> 4, lm = lane & 15;
  const int m0 = blockIdx.x * 64;

  if (t < 64)       ioff[t] = dst[m0 + t];
  else if (t < 128) ioff[t] = src[m0 + t - 64];
  __syncthreads();

  // ---- Gather: 16 wave-coalesced 1 KB loads in flight, then swizzled LDS writes
  {
    const int c = lane, half = (c >= 32) ? 64 : 0, cc = c & 31;
    short8 g[16];
#pragma unroll
    for (int it = 0; it < 16; ++it) {
      int node = ioff[half + it * 4 + w];
      g[it] = ((const short8*)hbf)[node * 32 + cc];
    }
#pragma unroll
    for (int it = 0; it < 16; ++it) {
      int r = it * 4 + w;
      *(short8*)&A[r * 512 + ((c ^ sw3(r)) << 3)] = g[it];
    }
  }

  floatx4 acc[4][4];
#pragma unroll
  for (int i = 0; i < 4; ++i)
#pragma unroll
    for (int j = 0; j < 4; ++j) acc[i][j] = (floatx4)(0.0f);
  __syncthreads();

  const short8* B1 = (const short8*)W1F;
  const short8* B2 = (const short8*)W2F;

  // ---- Layer 1: K=512, 16 k-steps, B-ring depth 4
  {
    short8 bq[4][4];
#pragma unroll
    for (int s = 0; s < 4; ++s)
#pragma unroll
      for (int jt = 0; jt < 4; ++jt)
        bq[s][jt] = B1[(s * 256 + w * 64 + jt * 16 + lm) * 4 + lq];

#pragma unroll
    for (int s = 0; s < 16; ++s) {
#pragma unroll
      for (int i = 0; i < 4; ++i) {
        int r = i * 16 + lm, cch = s * 4 + lq;
        short8 af = *(const short8*)&A[r * 512 + ((cch ^ sw3(r)) << 3)];
#pragma unroll
        for (int j = 0; j < 4; ++j)
          acc[i][j] = __builtin_amdgcn_mfma_f32_16x16x32_bf16(af, bq[s & 3][j], acc[i][j], 0, 0, 0);
      }
      if (s < 12)
#pragma unroll
        for (int jt = 0; jt < 4; ++jt)
          bq[s & 3][jt] = B1[((s + 4) * 256 + w * 64 + jt * 16 + lm) * 4 + lq];
    }
  }
  __syncthreads();
  // Epilogue 1: relu -> X (C/D map: col=lane&15 (feature), row=quad*4+reg (edge))
#pragma unroll
  for (int i = 0; i < 4; ++i) {
    int row0 = i * 16 + lq * 4;
#pragma unroll
    for (int j = 0; j < 4; ++j) {
      int col = w * 64 + j * 16 + lm, c8 = col >> 3, ce = col & 7;
#pragma unroll
      for (int rg = 0; rg < 4; ++rg) {
        int row = row0 + rg;
        float v = acc[i][j][rg];
        v = v > 0.0f ? v : 0.0f;
        X[row * 256 + (((c8 ^ sw3(row)) << 3) | ce)] = f2bf(v);
      }
    }
  }
#pragma unroll
  for (int i = 0; i < 4; ++i)
#pragma unroll
    for (int j = 0; j < 4; ++j) acc[i][j] = (floatx4)(0.0f);
  __syncthreads();

  // ---- Layer 2: K=256, 8 k-steps, B-ring depth 4
  {
    short8 bq[4][4];
#pragma unroll
    for (int s = 0; s < 4; ++s)
#pragma unroll
      for (int jt = 0; jt < 4; ++jt)
        bq[s][jt] = B2[(s * 256 + w * 64 + jt * 16 + lm) * 4 + lq];

#pragma unroll
    for (int s = 0; s < 8; ++s) {
#pragma unroll
      for (int i = 0; i < 4; ++i) {
        int r = i * 16 + lm, cch = s * 4 + lq;
        short8 af = *(const short8*)&X[r * 256 + ((cch ^ sw3(r)) << 3)];
#pragma unroll
        for (int j = 0; j < 4; ++j)
          acc[i][j] = __builtin_amdgcn_mfma_f32_16x16x32_bf16(af, bq[s & 3][j], acc[i][j], 0, 0, 0);
      }
      if (s < 4)
#pragma unroll
        for (int jt = 0; jt < 4; ++jt)
          bq[s & 3][jt] = B2[((s + 4) * 256 + w * 64 + jt * 16 + lm) * 4 + lq];
    }
  }
  __syncthreads();
  // Epilogue 2: relu -> X2
#pragma unroll
  for (int i = 0; i < 4; ++i) {
    int row0 = i * 16 + lq * 4;
#pragma unroll
    for (int j = 0; j < 4; ++j) {
      int col = w * 64 + j * 16 + lm, c8 = col >> 3, ce = col & 7;
#pragma unroll
      for (int rg = 0; rg < 4; ++rg) {
        int row = row0 + rg;
        float v = acc[i][j][rg];
        v = v > 0.0f ? v : 0.0f;
        X2[row * 256 + (((c8 ^ sw3(row)) << 3) | ce)] = f2bf(v);
      }
    }
  }
  __syncthreads();

  // ---- Layer 3: out = X2 @ W3 via MFMA (N padded to 16; cols 0,1 valid)
  {
    floatx4 a3 = (floatx4)(0.0f);
    const short8* B3 = (const short8*)W3F;
#pragma unroll
    for (int s = 0; s < 8; ++s) {
      short8 b3 = B3[s * 64 + lane];              // 1 KB coalesced, L2-hot
      int r = w * 16 + lm, cch = s * 4 + lq;
      short8 af = *(const short8*)&X2[r * 256 + ((cch ^ sw3(r)) << 3)];
      a3 = __builtin_amdgcn_mfma_f32_16x16x32_bf16(af, b3, a3, 0, 0, 0);
    }
    if (lm < 2) {
#pragma unroll
      for (int rg = 0; rg < 4; ++rg)
        out[(m0 + w * 16 + lq * 4 + rg) * 2 + lm] = a3[rg];
    }
  }
}

// ---- legacy weight-frag kernel (fallback path only) ----
__global__ void wfrag_kernel(const float* __restrict__ W,
                             unsigned short* __restrict__ out, int total) {
  int u = blockIdx.x * 256 + threadIdx.x;
  if (u >= total) return;
  int j = u & 7, kq = (u >> 3) & 3, n = (u >> 5) & 255, k32 = u >> 13;
  out[u] = f2bf(W[(k32 * 32 + kq * 8 + j) * 256 + n]);
}

// ---- fp32-gather fallback (tiny workspace) ----
__global__ __launch_bounds__(256, 2)
void edge_mlp_fb(const float* __restrict__ h,
                 const int* __restrict__ dst,
                 const int* __restrict__ src,
                 const unsigned short* __restrict__ W1F,
                 const unsigned short* __restrict__ W2F,
                 const float* __restrict__ W3,
                 float* __restrict__ out) {
  __shared__ unsigned short A[64 * 512];
  __shared__ float w3s[512];
  __shared__ int ioff[128];
  unsigned short* X = A;
  const int t = threadIdx.x, lane = t & 63, w = t >> 6;
  const int lq = lane >> 4, lm = lane & 15;
  const int m0 = blockIdx.x * 64;
  if (t < 64) ioff[t] = dst[m0 + t];
  else if (t < 128) ioff[t] = src[m0 + t - 64];
  w3s[t] = W3[t];
  w3s[t + 256] = W3[t + 256];
  __syncthreads();
  {
    const int c = lane, half = (c >= 32) ? 64 : 0, cc = c & 31;
#pragma unroll
    for (int it = 0; it < 16; ++it) {
      int r = it * 4 + w;
      int node = ioff[half + r];
      const float4* h4 = (const float4*)h;
      float4 v0 = h4[node * 64 + cc * 2], v1 = h4[node * 64 + cc * 2 + 1];
      short8 v;
      v[0] = (short)f2bf(v0.x); v[1] = (short)f2bf(v0.y);
      v[2] = (short)f2bf(v0.z); v[3] = (short)f2bf(v0.w);
      v[4] = (short)f2bf(v1.x); v[5] = (short)f2bf(v1.y);
      v[6] = (short)f2bf(v1.z); v[7] = (short)f2bf(v1.w);
      *(short8*)&A[r * 512 + ((c ^ (r & 7)) << 3)] = v;
    }
  }
  floatx4 acc[4][4];
#pragma unroll
  for (int i = 0; i < 4; ++i)
#pragma unroll
    for (int j = 0; j < 4; ++j) acc[i][j] = (floatx4)(0.0f);
  __syncthreads();
  const short8* B1 = (const short8*)W1F;
  const short8* B2 = (const short8*)W2F;
#pragma unroll
  for (int k32 = 0; k32 < 16; ++k32) {
    short8 b[4], af[4];
#pragma unroll
    for (int jt = 0; jt < 4; ++jt)
      b[jt] = B1[(k32 * 256 + w * 64 + jt * 16 + lm) * 4 + lq];
#pragma unroll
    for (int i = 0; i < 4; ++i) {
      int r = i * 16 + lm, c = k32 * 4 + lq;
      af[i] = *(const short8*)&A[r * 512 + ((c ^ (r & 7)) << 3)];
    }
#pragma unroll
    for (int i = 0; i < 4; ++i)
#pragma unroll
      for (int j = 0; j < 4; ++j)
        acc[i][j] = __builtin_amdgcn_mfma_f32_16x16x32_bf16(af[i], b[j], acc[i][j], 0, 0, 0);
  }
  __syncthreads();
#pragma unroll
  for (int i = 0; i < 4; ++i) {
    int row0 = i * 16 + lq * 4;
#pragma unroll
    for (int j = 0; j < 4; ++j) {
      int col = w * 64 + j * 16 + lm, c8 = col >> 3, ce = col & 7;
#pragma unroll
      for (int rg = 0; rg < 4; ++rg) {
        int row = row0 + rg;
        float v = acc[i][j][rg];
        v = v > 0.0f ? v : 0.0f;
        X[row * 256 + (((c8 ^ (row & 7)) << 3) | ce)] = f2bf(v);
      }
    }
  }
#pragma unroll
  for (int i = 0; i < 4; ++i)
#pragma unroll
    for (int j = 0; j < 4; ++j) acc[i][j] = (floatx4)(0.0f);
  __syncthreads();
#pragma unroll
  for (int k32 = 0; k32 < 8; ++k32) {
    short8 b[4], af[4];
#pragma unroll
    for (int jt = 0; jt < 4; ++jt)
      b[jt] = B2[(k32 * 256 + w * 64 + jt * 16 + lm) * 4 + lq];
#pragma unroll
    for (int i = 0; i < 4; ++i) {
      int r = i * 16 + lm, c = k32 * 4 + lq;
      af[i] = *(const short8*)&X[r * 256 + ((c ^ (r & 7)) << 3)];
    }
#pragma unroll
    for (int i = 0; i < 4; ++i)
#pragma unroll
      for (int j = 0; j < 4; ++j)
        acc[i][j] = __builtin_amdgcn_mfma_f32_16x16x32_bf16(af[i], b[j], acc[i][j], 0, 0, 0);
  }
  __syncthreads();
#pragma unroll
  for (int i = 0; i < 4; ++i) {
    int row0 = i * 16 + lq * 4;
#pragma unroll
    for (int j = 0; j < 4; ++j) {
      int col = w * 64 + j * 16 + lm, c8 = col >> 3, ce = col & 7;
#pragma unroll
      for (int rg = 0; rg < 4; ++rg) {
        int row = row0 + rg;
        float v = acc[i][j][rg];
        v = v > 0.0f ? v : 0.0f;
        X[row * 256 + (((c8 ^ (row & 7)) << 3) | ce)] = f2bf(v);
      }
    }
  }
  __syncthreads();
  {
    int r = t >> 2, o = (t >> 1) & 1, hh = t & 1;
    float s = 0.0f;
#pragma unroll
    for (int it = 0; it < 16; ++it) {
      int c = hh * 16 + it;
      short8 xv = *(const short8*)&X[r * 256 + ((c ^ (r & 7)) << 3)];
#pragma unroll
      for (int e = 0; e < 8; ++e)
        s += bf2f((unsigned short)xv[e]) * w3s[((c << 3) + e) * 2 + o];
    }
    s += __shfl_xor(s, 1);
    if (hh == 0) out[(m0 + r) * 2 + o] = s;
  }
}

extern "C" void kernel_launch(void* const* d_in, const int* in_sizes, int n_in,
                              void* d_out, int out_size, void* d_ws, size_t ws_size,
                              hipStream_t stream) {
  const float* h   = (const float*)d_in[0];
  const int*   dst = (const int*)d_in[1];
  const int*   src = (const int*)d_in[2];
  const float* W1  = (const float*)d_in[3];
  const float* W2  = (const float*)d_in[4];
  const float* W3  = (const float*)d_in[5];
  float* out = (float*)d_out;

  const int h_elems = in_sizes[0];
  const int n_pairs = in_sizes[1];
  const int ntiles  = n_pairs / 64;

  const size_t hbf_elems = (size_t)h_elems;
  const bool use_hbf =
      ws_size >= (hbf_elems + 131072 + 65536 + 4096) * sizeof(unsigned short);

  unsigned short* HBF = (unsigned short*)d_ws;
  unsigned short* W1F = HBF + hbf_elems;
  unsigned short* W2F = W1F + 131072;
  unsigned short* W3F = W2F + 65536;

  if (use_hbf) {
    int nh4 = h_elems / 4;
    int grid = 512 + 256 + 16 + (nh4 + 255) / 256;
    prep_kernel<<<grid, 256, 0, stream>>>(h, W1, W2, W3, HBF, W1F, W2F, W3F, nh4);
    edge_mlp3<<<ntiles, 256, 0, stream>>>(HBF, dst, src, W1F, W2F, W3F, out);
  } else {
    unsigned short* W1Fb = (unsigned short*)d_ws;
    unsigned short* W2Fb = W1Fb + 131072;
    wfrag_kernel<<<512, 256, 0, stream>>>(W1, W1Fb, 131072);
    wfrag_kernel<<<256, 256, 0, stream>>>(W2, W2Fb, 65536);
    edge_mlp_fb<<<ntiles, 256, 0, stream>>>(h, dst, src, W1Fb, W2Fb, W3, out);
  }
}